// Round 2
// baseline (382.456 us; speedup 1.0000x reference)
//
#include <hip/hip_runtime.h>
#include <math.h>

#define NCLS 80
#define KTOP 10
#define NB 32
#define NA 8400
#define NM 64
#define F_EPS 1e-9f
#define F_KEPS 1e-7f

// ---------------------------------------------------------------------------
// CIoU between gt box (gx0,gy0,gx1,gy1) and pred box pb, with the pred-side
// atan (atan(w2/h2)) precomputed. Matches reference compute_ciou exactly,
// with ov^6 computed by multiplication (sign behavior of pow(neg, 6.0)).
// ---------------------------------------------------------------------------
__device__ __forceinline__ float ciou_one(float gx0, float gy0, float gx1, float gy1,
                                          float area1, float atanG,
                                          float4 pb, float atanP_a)
{
    float w2 = pb.z - pb.x;
    float h2 = pb.w - pb.y + F_KEPS;
    float ix = fminf(gx1, pb.z) - fmaxf(gx0, pb.x);
    float iy = fminf(gy1, pb.w) - fmaxf(gy0, pb.y);
    float inter = fmaxf(ix, 0.f) * fmaxf(iy, 0.f);
    float uni = area1 + w2 * h2 - inter + F_KEPS;
    float iou = inter / uni;
    float cw = fmaxf(gx1, pb.z) - fminf(gx0, pb.x);
    float ch = fmaxf(gy1, pb.w) - fminf(gy0, pb.y);
    float c2 = cw * cw + ch * ch + F_KEPS;
    float dx = pb.x + pb.z - gx0 - gx1;
    float dy = pb.y + pb.w - gy0 - gy1;
    float rho2 = (dx * dx + dy * dy) * 0.25f;
    float dv = atanP_a - atanG;
    const float c4pi2 = 4.0f / (float)(M_PI * M_PI);
    float v = c4pi2 * dv * dv;
    float alpha = v / (v - iou + (1.0f + F_KEPS));
    return iou - (rho2 / c2 + v * alpha);
}

// ---------------------------------------------------------------------------
// k_pre: (1) detect bool-mask storage (int32 vs byte) -> flag
//        (2) atanP[b*A+a] = atan(w2/h2) for every predicted box
// ---------------------------------------------------------------------------
__global__ __launch_bounds__(256) void k_pre(const float* __restrict__ dbox,
                                             const unsigned int* __restrict__ gtm_words,
                                             float* __restrict__ atanP,
                                             int* __restrict__ flag)
{
    int i = blockIdx.x * 256 + threadIdx.x;
    if (blockIdx.x == 0) {
        // First 2048 bytes viewed as 512 u32 words. int32-stored bools are all
        // 0/1; byte-packed bools give words with nonzero high bytes (p≈0.992/word).
        __shared__ int s_bad;
        if (threadIdx.x == 0) s_bad = 0;
        __syncthreads();
        unsigned int w0 = gtm_words[threadIdx.x];
        unsigned int w1 = gtm_words[threadIdx.x + 256];
        if (w0 > 1u || w1 > 1u) s_bad = 1;
        __syncthreads();
        if (threadIdx.x == 0) *flag = s_bad ? 0 : 1;  // 1 => int32 storage
    }
    if (i < NB * NA) {
        float4 pb = ((const float4*)dbox)[i];
        float w2 = pb.z - pb.x;
        float h2 = pb.w - pb.y + F_KEPS;
        atanP[i] = atanf(w2 / h2);
    }
}

// ---------------------------------------------------------------------------
// k_align: one block per (b,m). Computes alignment over all A anchors into
// LDS, then 10 rounds of block-argmax (stable lowest-index tie-break ==
// lax.top_k), then recomputes CIoU for the <=10 selected anchors and writes
// the candidate table: idx, overlap, contrib = align * max_ov/(max_align+eps).
// LDS ~35.8 KB -> 4 blocks/CU.
// ---------------------------------------------------------------------------
__global__ __launch_bounds__(256) void k_align(const float* __restrict__ scores,
    const float* __restrict__ dbox, const float* __restrict__ anchors,
    const int* __restrict__ gtl, const float* __restrict__ gtb,
    const void* __restrict__ gtm, const float* __restrict__ atanP,
    const int* __restrict__ flag,
    int* __restrict__ cand_idx, float* __restrict__ cand_ov, float* __restrict__ cand_ct)
{
    __shared__ float s_al[NA];
    __shared__ float s_rv[256];
    __shared__ int   s_ri[256];
    __shared__ int   s_si[KTOP];
    __shared__ float s_sa[KTOP];
    __shared__ float s_so[KTOP];

    const int bm = blockIdx.x;
    const int b = bm >> 6;       // NM == 64
    const int tid = threadIdx.x;

    bool maskv;
    if (*flag) maskv = ((const int*)gtm)[bm] != 0;
    else       maskv = ((const unsigned char*)gtm)[bm] != 0;

    if (!maskv) {   // uniform across block: whole row zero, no candidates
        if (tid < KTOP) {
            cand_idx[bm * KTOP + tid] = -1;
            cand_ov [bm * KTOP + tid] = 0.f;
            cand_ct [bm * KTOP + tid] = 0.f;
        }
        return;
    }

    const float gx0 = gtb[bm * 4 + 0], gy0 = gtb[bm * 4 + 1];
    const float gx1 = gtb[bm * 4 + 2], gy1 = gtb[bm * 4 + 3];
    const int lbl = max(gtl[bm], 0);
    const float w1 = gx1 - gx0;
    const float h1 = gy1 - gy0 + F_KEPS;
    const float atanG = atanf(w1 / h1);
    const float area1 = w1 * h1;

    const float*  sb  = scores + (size_t)b * NA * NCLS;
    const float4* pbv = (const float4*)dbox + (size_t)b * NA;
    const float*  atp = atanP + (size_t)b * NA;

    for (int a = tid; a < NA; a += 256) {
        float4 pb = pbv[a];
        float2 an = ((const float2*)anchors)[a];
        float ov = ciou_one(gx0, gy0, gx1, gy1, area1, atanG, pb, atp[a]);
        float sc = sb[a * NCLS + lbl];
        float t2 = ov * ov;
        float ov6 = t2 * t2 * t2;                 // pow(ov, 6.0): even power
        float al = sqrtf(sc) * ov6;               // pow(sc, 0.5)
        bool inb = (gx0 < an.x) && (gy0 < an.y) && (gx1 > an.x) && (gy1 > an.y);
        s_al[a] = inb ? al : 0.f;
    }
    __syncthreads();

    // 10 rounds of block argmax with lowest-index tie-break (== lax.top_k order)
    for (int k = 0; k < KTOP; ++k) {
        float bv = -1.f; int bi = NA;
        for (int a = tid; a < NA; a += 256) {
            float v = s_al[a];
            if (v > bv) { bv = v; bi = a; }       // ascending a: keeps lowest idx
        }
        s_rv[tid] = bv; s_ri[tid] = bi;
        __syncthreads();
        for (int s = 128; s > 0; s >>= 1) {
            if (tid < s) {
                float v2 = s_rv[tid + s]; int i2 = s_ri[tid + s];
                if (v2 > s_rv[tid] || (v2 == s_rv[tid] && i2 < s_ri[tid])) {
                    s_rv[tid] = v2; s_ri[tid] = i2;
                }
            }
            __syncthreads();
        }
        if (tid == 0) {
            float best = s_rv[0]; int bidx = s_ri[0];
            if (best > 0.f) {                      // cand_metrics > 0 filter
                s_si[k] = bidx; s_sa[k] = best;
                s_al[bidx] = -1.f;                 // exclude from later rounds
            } else {
                s_si[k] = -1; s_sa[k] = 0.f;
            }
        }
        __syncthreads();
    }

    // recompute overlap for the selected anchors (K threads in parallel)
    if (tid < KTOP) {
        int id = s_si[tid];
        float ov = 0.f;
        if (id >= 0)
            ov = ciou_one(gx0, gy0, gx1, gy1, area1, atanG, pbv[id], atp[id]);
        s_so[tid] = ov;
    }
    __syncthreads();

    if (tid == 0) {
        float max_al = (s_si[0] >= 0) ? s_sa[0] : 0.f;   // top-1 alignment
        float max_ov = 0.f;                               // max(0, matched ovs)
        for (int k = 0; k < KTOP; ++k)
            if (s_si[k] >= 0) max_ov = fmaxf(max_ov, s_so[k]);
        float ratio = max_ov / (max_al + F_EPS);
        for (int k = 0; k < KTOP; ++k) {
            int id = s_si[k];
            cand_idx[bm * KTOP + k] = id;
            cand_ov [bm * KTOP + k] = (id >= 0) ? s_so[k] : 0.f;
            cand_ct [bm * KTOP + k] = (id >= 0) ? s_sa[k] * ratio : 0.f;
        }
    }
}

// ---------------------------------------------------------------------------
// k_out: grid (ceil(A/256), B). Loads the batch's 640-entry candidate table
// into LDS, zero-fills this block's class_target rows, then per anchor:
// argmax over m of matched overlap (first-index tie-break), match mask,
// bbox labels, (gt_match>0), and the one-hot * norm_align scatter.
// ---------------------------------------------------------------------------
__global__ __launch_bounds__(256) void k_out(const float* __restrict__ gtb,
    const int* __restrict__ gtl,
    const int* __restrict__ cand_idx, const float* __restrict__ cand_ov,
    const float* __restrict__ cand_ct,
    float* __restrict__ out_bbox, float* __restrict__ out_cls,
    float* __restrict__ out_match)
{
    __shared__ int   s_idx[NM * KTOP];
    __shared__ float s_ov [NM * KTOP];
    __shared__ float s_ct [NM * KTOP];
    const int b  = blockIdx.y;
    const int a0 = blockIdx.x * 256;
    const int tid = threadIdx.x;
    const int a  = a0 + tid;

    for (int i = tid; i < NM * KTOP; i += 256) {
        s_idx[i] = cand_idx[b * NM * KTOP + i];
        s_ov [i] = cand_ov [b * NM * KTOP + i];
        s_ct [i] = cand_ct [b * NM * KTOP + i];
    }

    // coalesced zero-fill of this block's class-target rows
    const int nA = min(256, NA - a0);
    float4* cb = (float4*)(out_cls + ((size_t)b * NA + a0) * NCLS);
    const int nW = nA * NCLS / 4;
    for (int i = tid; i < nW; i += 256) cb[i] = make_float4(0.f, 0.f, 0.f, 0.f);

    __syncthreads();   // LDS table ready AND zero-fill complete before scatter

    if (a < NA) {
        float best = -INFINITY; int gm = 0; float normv = 0.f;
        for (int m = 0; m < NM; ++m) {
            float v = 0.f, ct = 0.f;
            for (int k = 0; k < KTOP; ++k) {
                int id = s_idx[m * KTOP + k];
                bool hit = (id == a);
                v  = hit ? s_ov[m * KTOP + k] : v;
                ct = hit ? s_ct[m * KTOP + k] : ct;
            }
            if (v > best) { best = v; gm = m; }  // strict >: first-index argmax
            normv = fmaxf(normv, ct);
        }
        bool mask = best > 0.f;
        float4 bb = mask ? ((const float4*)gtb)[b * NM + gm]
                         : make_float4(-1.f, -1.f, -1.f, -1.f);
        ((float4*)out_bbox)[(size_t)b * NA + a] = bb;
        out_match[(size_t)b * NA + a] = (gm > 0) ? 1.f : 0.f;
        if (mask) {
            int c = gtl[b * NM + gm];
            out_cls[(((size_t)b * NA + a) * NCLS) + c] = normv;
        }
    }
}

extern "C" void kernel_launch(void* const* d_in, const int* in_sizes, int n_in,
                              void* d_out, int out_size, void* d_ws, size_t ws_size,
                              hipStream_t stream)
{
    const float* scores  = (const float*)d_in[0];
    const float* dbox    = (const float*)d_in[1];
    const float* anchors = (const float*)d_in[2];
    const int*   gtl     = (const int*)d_in[3];
    const float* gtb     = (const float*)d_in[4];
    const void*  gtm     = d_in[5];

    // workspace layout
    char* ws = (char*)d_ws;
    int*   flag  = (int*)ws;
    float* atanP = (float*)(ws + 16);
    char* p = ws + 16 + (size_t)NB * NA * 4;
    int*   cand_idx = (int*)p;    p += (size_t)NB * NM * KTOP * 4;
    float* cand_ov  = (float*)p;  p += (size_t)NB * NM * KTOP * 4;
    float* cand_ct  = (float*)p;

    float* out_bbox  = (float*)d_out;
    float* out_cls   = out_bbox + (size_t)NB * NA * 4;
    float* out_match = out_cls + (size_t)NB * NA * NCLS;

    k_pre<<<(NB * NA + 255) / 256, 256, 0, stream>>>(
        dbox, (const unsigned int*)gtm, atanP, flag);
    k_align<<<NB * NM, 256, 0, stream>>>(
        scores, dbox, anchors, gtl, gtb, gtm, atanP, flag,
        cand_idx, cand_ov, cand_ct);
    k_out<<<dim3((NA + 255) / 256, NB), 256, 0, stream>>>(
        gtb, gtl, cand_idx, cand_ov, cand_ct, out_bbox, out_cls, out_match);
}